// Round 5
// baseline (109.720 us; speedup 1.0000x reference)
//
#include <hip/hip_runtime.h>
#include <stdint.h>

// Problem constants (fixed by setup_inputs)
#define NB 32
#define NC 128
#define NH 56
#define NW 56
#define NHW_ (NH * NW)      // 3136
#define NPIX (NB * NHW_)    // 100352
#define NO 128
#define NK 1152             // NC * 9
#define NSTRIP 14           // NH / 4
#define NSLOT (NB * NSTRIP) // 448 partial slots per channel

// Padded bitplane grid: h in [-1,56] -> 58 rows, w in [-1,64] -> 66 cols
// (cols padded past 56 so lanes 56..63 read in-bounds zeros).
#define PADH 58
#define PADW 66
#define PAD_BYTES ((size_t)NB * PADH * PADW * 2 * 8)  // 1,959,936

typedef unsigned long long u64;

__device__ __forceinline__ size_t pidx(int n, int h, int w) {
    return (((size_t)n * PADH + (h + 1)) * PADW + (w + 1)) * 2;
}

// ---------------------------------------------------------------------------
// K1: sign(x + bias0) packed into 128-bit-per-pixel bitplanes (padded layout;
// border stays zero from the per-call memset).
// ---------------------------------------------------------------------------
__global__ __launch_bounds__(256) void pack_act(const float* __restrict__ x,
                                                const float* __restrict__ bias0,
                                                u64* __restrict__ packAp) {
    int p = blockIdx.x * 256 + threadIdx.x;
    if (p >= NPIX) return;
    int n = p / NHW_;
    int rem = p - n * NHW_;
    int h = rem / NW, wcol = rem - h * NW;
    const float* xb = x + (size_t)n * NC * NHW_ + rem;
    u64 w0 = 0, w1 = 0;
#pragma unroll 8
    for (int c = 0; c < 64; ++c)
        w0 |= (u64)((xb[(size_t)c * NHW_] + bias0[c]) > 0.f) << c;
#pragma unroll 8
    for (int c = 0; c < 64; ++c)
        w1 |= (u64)((xb[(size_t)(c + 64) * NHW_] + bias0[c + 64]) > 0.f) << c;
    size_t idx = pidx(n, h, wcol);
    packAp[idx]     = w0;
    packAp[idx + 1] = w1;
}

// ---------------------------------------------------------------------------
// K2: weight scale (mean |w|) + sign bitplanes + border correction table.
// corrW[o][0..7] = {sumL,sumR,sumT,sumB,c0,c2,c6,c8}, cv[t] = 128-2*popc(w_t).
// ---------------------------------------------------------------------------
__global__ __launch_bounds__(64) void pack_wgt(const float* __restrict__ w,
                                               u64* __restrict__ packW,
                                               float* __restrict__ scaleW,
                                               int* __restrict__ corrW) {
    __shared__ u64 sb[18];
    int o = blockIdx.x;
    int t = threadIdx.x;  // 64 threads
    const float* wo = w + (size_t)o * NK;
    float s = 0.f;
    for (int i = t; i < NK; i += 64) s += fabsf(wo[i]);
    for (int off = 32; off; off >>= 1) s += __shfl_down(s, off);
    if (t == 0) scaleW[o] = s / (float)NK;
    if (t < 18) {
        int tap = t >> 1;
        int j   = t & 1;
        u64 bits = 0;
        for (int cc = 0; cc < 64; ++cc) {
            int c = j * 64 + cc;
            bits |= (u64)(wo[c * 9 + tap] > 0.f) << cc;
        }
        packW[(size_t)o * 18 + t] = bits;
        sb[t] = bits;
    }
    __syncthreads();
    if (t == 0) {
        int cv[9];
#pragma unroll
        for (int tap = 0; tap < 9; ++tap)
            cv[tap] = NC - 2 * (__popcll(sb[2 * tap]) + __popcll(sb[2 * tap + 1]));
        int* cw = corrW + o * 8;
        cw[0] = cv[0] + cv[3] + cv[6];  // sumL (kw=0 col)
        cw[1] = cv[2] + cv[5] + cv[8];  // sumR (kw=2 col)
        cw[2] = cv[0] + cv[1] + cv[2];  // sumT (kh=0 row)
        cw[3] = cv[6] + cv[7] + cv[8];  // sumB (kh=2 row)
        cw[4] = cv[0];                  // corner overlaps
        cw[5] = cv[2];
        cw[6] = cv[6];
        cw[7] = cv[8];
    }
}

// ---------------------------------------------------------------------------
// K3: binary conv. Block = 128 threads (2 waves), each wave owns 16 channels;
// block covers (n, 4-row strip, 32-channel pair-group). Grid 32*14*4 = 1792.
// Activations: 36 u64 loaded unconditionally from padded packA and PINNED in
// VGPRs via empty asm (defeats rematerialization). Border via corr subtract.
// MODE 0: store yI + partial stats. MODE 1: stats only. MODE 2: epilogue only.
// ---------------------------------------------------------------------------
template <int MODE>
__global__ __launch_bounds__(128, 4) void conv_bin(
    const u64* __restrict__ packAp, const u64* __restrict__ packW,
    const int* __restrict__ corrW, short* __restrict__ yI,
    int* __restrict__ sumP, int* __restrict__ sqP,
    const float* __restrict__ coefA, const float* __restrict__ coefB,
    const float* __restrict__ alpha, const float* __restrict__ bias2,
    const float* __restrict__ x, float* __restrict__ out) {
    __shared__ u64 lw[32 * 18];  // 4608 B
    __shared__ int lc[32 * 8];   // 1024 B

    int bid = blockIdx.x;
    int n = bid / (NSTRIP * 4);
    int rem = bid - n * (NSTRIP * 4);
    int strip = rem >> 2;
    int cgp = rem & 3;
    int obase = cgp * 32;
    int h0 = strip * 4;

    for (int i = threadIdx.x; i < 32 * 18; i += 128) lw[i] = packW[(size_t)obase * 18 + i];
    for (int i = threadIdx.x; i < 32 * 8; i += 128) lc[i] = corrW[obase * 8 + i];

    int wv = threadIdx.x >> 6, lane = threadIdx.x & 63;
    bool act = lane < NW;

    // 6 input rows (h0-1..h0+4) x 3 cols x 2 words = 72 VGPRs, unconditional.
    u64 a[6][3][2];
    const u64* bp = packAp + (((size_t)n * PADH + h0) * PADW + lane) * 2;
#pragma unroll
    for (int r = 0; r < 6; ++r)
#pragma unroll
        for (int c = 0; c < 3; ++c) {
            ulonglong2 q = *reinterpret_cast<const ulonglong2*>(bp + ((size_t)r * PADW + c) * 2);
            a[r][c][0] = q.x;
            a[r][c][1] = q.y;
        }
    // Pin: compiler must keep these resident (no remat of the loads).
#pragma unroll
    for (int r = 0; r < 6; ++r)
#pragma unroll
        for (int c = 0; c < 3; ++c)
            asm volatile("" : "+v"(a[r][c][0]), "+v"(a[r][c][1]));
    __syncthreads();

    bool top = (strip == 0), bot = (strip == NSTRIP - 1);
    bool isL = (lane == 0), isR = (lane == NW - 1);
    int sl = n * NSTRIP + strip;
    short* ybase = yI + (size_t)n * NO * NHW_ + (size_t)h0 * NW + lane;

    for (int oo = 0; oo < 16; ++oo) {
        int lo = (wv << 4) + oo;       // local channel 0..31
        int o = obase + lo;            // global channel
        const u64* wp = &lw[lo * 18];
        int pc0 = 0, pc1 = 0, pc2 = 0, pc3 = 0;
#pragma unroll
        for (int t = 0; t < 9; ++t) {
            const int kh = t / 3, kw = t - 3 * (t / 3);
            u64 w0 = wp[2 * t], w1 = wp[2 * t + 1];
            pc0 += __popcll(a[kh][kw][0] ^ w0) + __popcll(a[kh][kw][1] ^ w1);
            pc1 += __popcll(a[kh + 1][kw][0] ^ w0) + __popcll(a[kh + 1][kw][1] ^ w1);
            pc2 += __popcll(a[kh + 2][kw][0] ^ w0) + __popcll(a[kh + 2][kw][1] ^ w1);
            pc3 += __popcll(a[kh + 3][kw][0] ^ w0) + __popcll(a[kh + 3][kw][1] ^ w1);
        }
        const int* cw = &lc[lo * 8];
        int corrcol = isL ? cw[0] : (isR ? cw[1] : 0);
        int base = NK - corrcol;
        int d0 = base - 2 * pc0;
        int d1 = base - 2 * pc1;
        int d2 = base - 2 * pc2;
        int d3 = base - 2 * pc3;
        if (top) d0 -= cw[2] - (isL ? cw[4] : (isR ? cw[5] : 0));
        if (bot) d3 -= cw[3] - (isL ? cw[6] : (isR ? cw[7] : 0));

        if (MODE == 0 && act) {
            short* yp = ybase + (size_t)o * NHW_;
            yp[0]      = (short)d0;
            yp[NW]     = (short)d1;
            yp[2 * NW] = (short)d2;
            yp[3 * NW] = (short)d3;
        }
        if (MODE <= 1) {
            int s = act ? (d0 + d1 + d2 + d3) : 0;
            int q = act ? (__mul24(d0, d0) + __mul24(d1, d1) +
                           __mul24(d2, d2) + __mul24(d3, d3)) : 0;
#pragma unroll
            for (int off = 32; off; off >>= 1) {
                s += __shfl_down(s, off);
                q += __shfl_down(q, off);
            }
            if (lane == 0) {
                sumP[o * NSLOT + sl] = s;   // q <= 56*4*1152^2 = 2.97e8 < 2^31
                sqP[o * NSLOT + sl]  = q;
            }
        }
        if (MODE == 2 && act) {
            float ca = coefA[o], cb = coefB[o], al = alpha[o], b2 = bias2[o];
            size_t idx = ((size_t)n * NO + o) * NHW_ + (size_t)h0 * NW + lane;
            int dv[4] = {d0, d1, d2, d3};
#pragma unroll
            for (int r = 0; r < 4; ++r) {
                float tv = fmaf(ca, (float)dv[r], cb) + x[idx + (size_t)r * NW];
                tv = tv >= 0.f ? tv : al * tv;
                out[idx + (size_t)r * NW] = tv + b2;
            }
        }
    }
}

// ---------------------------------------------------------------------------
// K4: fold partial stats + scale + BN + bias1 into per-channel affine.
// 128 blocks x 64 threads; each block reduces 448 partials for one channel.
// ---------------------------------------------------------------------------
__global__ __launch_bounds__(64) void bn_coef2(const int* __restrict__ sumP,
                                               const int* __restrict__ sqP,
                                               const float* __restrict__ scaleW,
                                               const float* __restrict__ gamma,
                                               const float* __restrict__ beta,
                                               const float* __restrict__ bias1,
                                               float* __restrict__ coefA,
                                               float* __restrict__ coefB) {
    int o = blockIdx.x;
    int t = threadIdx.x;
    long long s = 0, q = 0;
    for (int i = t; i < NSLOT; i += 64) {
        s += sumP[o * NSLOT + i];
        q += sqP[o * NSLOT + i];
    }
#pragma unroll
    for (int off = 32; off; off >>= 1) {
        s += __shfl_down(s, off);
        q += __shfl_down(q, off);
    }
    if (t == 0) {
        double cnt = (double)NPIX;
        double mean = (double)s / cnt;
        double var = (double)q / cnt - mean * mean;
        if (var < 0.0) var = 0.0;
        float sc = scaleW[o];
        float rs = rsqrtf((float)((double)sc * (double)sc * var) + 1e-5f);
        float g = gamma[o];
        coefA[o] = sc * g * rs;
        coefB[o] = beta[o] - (float)((double)sc * mean) * g * rs + bias1[o];
    }
}

// ---------------------------------------------------------------------------
// K5: elementwise epilogue, 8 elems/thread vectorized.
// out = prelu(coefA*y + coefB + x) + bias2
// ---------------------------------------------------------------------------
__global__ __launch_bounds__(256) void final_store(const short* __restrict__ yI,
                                                   const float* __restrict__ x,
                                                   const float* __restrict__ coefA,
                                                   const float* __restrict__ coefB,
                                                   const float* __restrict__ alpha,
                                                   const float* __restrict__ bias2,
                                                   float* __restrict__ out) {
    const size_t ngroups = (size_t)NB * NO * NHW_ / 8;
    for (size_t g = (size_t)blockIdx.x * blockDim.x + threadIdx.x; g < ngroups;
         g += (size_t)gridDim.x * blockDim.x) {
        size_t i = g * 8;
        int o = (int)((i / NHW_) % NO);
        float a = coefA[o], bb = coefB[o], al = alpha[o], b2 = bias2[o];
        int4 yv = *reinterpret_cast<const int4*>(yI + i);
        float4 x0 = *reinterpret_cast<const float4*>(x + i);
        float4 x1 = *reinterpret_cast<const float4*>(x + i + 4);
        int q[4] = {yv.x, yv.y, yv.z, yv.w};
        float xs[8] = {x0.x, x0.y, x0.z, x0.w, x1.x, x1.y, x1.z, x1.w};
        float r[8];
#pragma unroll
        for (int j = 0; j < 4; ++j) {
            float lo = (float)(short)(q[j] & 0xffff);
            float hi = (float)(q[j] >> 16);
            float t0 = fmaf(a, lo, bb) + xs[2 * j];
            float t1 = fmaf(a, hi, bb) + xs[2 * j + 1];
            t0 = t0 >= 0.f ? t0 : al * t0;
            t1 = t1 >= 0.f ? t1 : al * t1;
            r[2 * j]     = t0 + b2;
            r[2 * j + 1] = t1 + b2;
        }
        float4 o0 = {r[0], r[1], r[2], r[3]};
        float4 o1 = {r[4], r[5], r[6], r[7]};
        *reinterpret_cast<float4*>(out + i)     = o0;
        *reinterpret_cast<float4*>(out + i + 4) = o1;
    }
}

// ---------------------------------------------------------------------------
// Workspace layout (bytes):
//   0        packAp  (padded bitplanes) 1,959,936
//   1959936  packW   (128*18 u64)          18,432
//   1978368  corrW   (128*8 i32)            4,096
//   1982464  scaleW  (128 f32)                512
//   1982976  coefA   (128 f32)                512
//   1983488  coefB   (128 f32)                512
//   1984000  sumP    (128*448 i32)        229,376
//   2213376  sqP     (128*448 i32)        229,376
//   2442752  yI      (int16)           25,690,112   -> total 28,132,864
// ---------------------------------------------------------------------------
extern "C" void kernel_launch(void* const* d_in, const int* in_sizes, int n_in,
                              void* d_out, int out_size, void* d_ws, size_t ws_size,
                              hipStream_t stream) {
    (void)in_sizes; (void)n_in; (void)out_size;
    const float* x     = (const float*)d_in[0];
    const float* bias0 = (const float*)d_in[1];
    const float* w     = (const float*)d_in[2];
    const float* gamma = (const float*)d_in[3];
    const float* beta  = (const float*)d_in[4];
    const float* bias1 = (const float*)d_in[5];
    const float* alpha = (const float*)d_in[6];
    const float* bias2 = (const float*)d_in[7];
    float* out = (float*)d_out;
    char* ws = (char*)d_ws;

    u64*   packAp = (u64*)ws;
    u64*   packW  = (u64*)(ws + 1959936);
    int*   corrW  = (int*)(ws + 1978368);
    float* scaleW = (float*)(ws + 1982464);
    float* coefA  = (float*)(ws + 1982976);
    float* coefB  = (float*)(ws + 1983488);
    int*   sumP   = (int*)(ws + 1984000);
    int*   sqP    = (int*)(ws + 2213376);
    short* yI     = (short*)(ws + 2442752);
    bool store = ws_size >= (size_t)2442752 + (size_t)NB * NO * NHW_ * 2;

    hipMemsetAsync(packAp, 0, PAD_BYTES, stream);
    pack_act<<<NPIX / 256, 256, 0, stream>>>(x, bias0, packAp);
    pack_wgt<<<NO, 64, 0, stream>>>(w, packW, scaleW, corrW);

    if (store) {
        conv_bin<0><<<NB * NSTRIP * 4, 128, 0, stream>>>(
            packAp, packW, corrW, yI, sumP, sqP,
            nullptr, nullptr, nullptr, nullptr, nullptr, nullptr);
        bn_coef2<<<NO, 64, 0, stream>>>(sumP, sqP, scaleW, gamma, beta, bias1, coefA, coefB);
        final_store<<<2048, 256, 0, stream>>>(yI, x, coefA, coefB, alpha, bias2, out);
    } else {
        conv_bin<1><<<NB * NSTRIP * 4, 128, 0, stream>>>(
            packAp, packW, corrW, nullptr, sumP, sqP,
            nullptr, nullptr, nullptr, nullptr, nullptr, nullptr);
        bn_coef2<<<NO, 64, 0, stream>>>(sumP, sqP, scaleW, gamma, beta, bias1, coefA, coefB);
        conv_bin<2><<<NB * NSTRIP * 4, 128, 0, stream>>>(
            packAp, packW, corrW, nullptr, sumP, sqP,
            coefA, coefB, alpha, bias2, x, out);
    }
}

// Round 6
// 100.269 us; speedup vs baseline: 1.0943x; 1.0943x over previous
//
#include <hip/hip_runtime.h>
#include <stdint.h>

// Problem constants (fixed by setup_inputs)
#define NB 32
#define NC 128
#define NH 56
#define NW 56
#define NHW_ (NH * NW)      // 3136
#define NPIX (NB * NHW_)    // 100352
#define NO 128
#define NK 1152             // NC * 9
#define NRP 28              // row pairs
#define NSLOT (NB * NRP)    // 896 partial slots per channel

// Padded bitplane grid: h in [-1,56] -> 58 rows, w in [-1,64] -> 66 cols
#define PADH 58
#define PADW 66
#define PAD_BYTES ((size_t)NB * PADH * PADW * 2 * 8)  // 1,959,936

typedef unsigned long long u64;

// ---------------------------------------------------------------------------
// K1: sign(x + bias0) packed into 128-bit-per-pixel bitplanes (padded layout;
// border stays zero from the per-call memset).
// ---------------------------------------------------------------------------
__global__ __launch_bounds__(256) void pack_act(const float* __restrict__ x,
                                                const float* __restrict__ bias0,
                                                u64* __restrict__ packAp) {
    int p = blockIdx.x * 256 + threadIdx.x;
    if (p >= NPIX) return;
    int n = p / NHW_;
    int rem = p - n * NHW_;
    int h = rem / NW, wcol = rem - h * NW;
    const float* xb = x + (size_t)n * NC * NHW_ + rem;
    u64 w0 = 0, w1 = 0;
#pragma unroll 8
    for (int c = 0; c < 64; ++c)
        w0 |= (u64)((xb[(size_t)c * NHW_] + bias0[c]) > 0.f) << c;
#pragma unroll 8
    for (int c = 0; c < 64; ++c)
        w1 |= (u64)((xb[(size_t)(c + 64) * NHW_] + bias0[c + 64]) > 0.f) << c;
    size_t idx = (((size_t)n * PADH + (h + 1)) * PADW + (wcol + 1)) * 2;
    packAp[idx]     = w0;
    packAp[idx + 1] = w1;
}

// ---------------------------------------------------------------------------
// K2: weight scale (mean |w|) + sign bitplanes + border correction table.
// corrW[o][0..7] = {sumL,sumR,sumT,sumB,c0,c2,c6,c8}, cv[t] = 128-2*popc(w_t).
// ---------------------------------------------------------------------------
__global__ __launch_bounds__(64) void pack_wgt(const float* __restrict__ w,
                                               u64* __restrict__ packW,
                                               float* __restrict__ scaleW,
                                               int* __restrict__ corrW) {
    __shared__ u64 sb[18];
    int o = blockIdx.x;
    int t = threadIdx.x;  // 64 threads
    const float* wo = w + (size_t)o * NK;
    float s = 0.f;
    for (int i = t; i < NK; i += 64) s += fabsf(wo[i]);
    for (int off = 32; off; off >>= 1) s += __shfl_down(s, off);
    if (t == 0) scaleW[o] = s / (float)NK;
    if (t < 18) {
        int tap = t >> 1;
        int j   = t & 1;
        u64 bits = 0;
        for (int cc = 0; cc < 64; ++cc) {
            int c = j * 64 + cc;
            bits |= (u64)(wo[c * 9 + tap] > 0.f) << cc;
        }
        packW[(size_t)o * 18 + t] = bits;
        sb[t] = bits;
    }
    __syncthreads();
    if (t == 0) {
        int cv[9];
#pragma unroll
        for (int tap = 0; tap < 9; ++tap)
            cv[tap] = NC - 2 * (__popcll(sb[2 * tap]) + __popcll(sb[2 * tap + 1]));
        int* cw = corrW + o * 8;
        cw[0] = cv[0] + cv[3] + cv[6];  // sumL (kw=0 col)
        cw[1] = cv[2] + cv[5] + cv[8];  // sumR (kw=2 col)
        cw[2] = cv[0] + cv[1] + cv[2];  // sumT (kh=0 row)
        cw[3] = cv[6] + cv[7] + cv[8];  // sumB (kh=2 row)
        cw[4] = cv[0];                  // corner overlaps
        cw[5] = cv[2];
        cw[6] = cv[6];
        cw[7] = cv[8];
    }
}

// ---------------------------------------------------------------------------
// K3: binary conv. Block = 256 threads (4 waves); block covers (n, 2-row
// pair, 64-channel group); each wave owns 16 channels. Grid 32*28*2 = 1792.
// Activation window a[4][3][2] = 48 VGPR (compiler-friendly, round-2 proven).
// Weights + corr read through wave-UNIFORM pointers -> scalar s_load, no LDS,
// no VGPR cost. Border via corr subtract (padded zeros + correction = exact).
// MODE 0: store yI + partial stats. MODE 1: stats only. MODE 2: epilogue.
// ---------------------------------------------------------------------------
template <int MODE>
__global__ __launch_bounds__(256) void conv_bin(
    const u64* __restrict__ packAp, const u64* __restrict__ packW,
    const int* __restrict__ corrW, short* __restrict__ yI,
    int* __restrict__ sumP, int* __restrict__ sqP,
    const float* __restrict__ coefA, const float* __restrict__ coefB,
    const float* __restrict__ alpha, const float* __restrict__ bias2,
    const float* __restrict__ x, float* __restrict__ out) {
    int bid = blockIdx.x;               // n*(NRP*2) + hp*2 + cg
    int n = bid / (NRP * 2);
    int rem = bid - n * (NRP * 2);
    int hp = rem >> 1;
    int cg = rem & 1;
    int h0 = hp * 2;

    int wv = threadIdx.x >> 6, lane = threadIdx.x & 63;
    bool act = lane < NW;

    // 4 input rows (h0-1..h0+2 = padded rows h0..h0+3) x 3 cols x 2 words.
    u64 a[4][3][2];
    const u64* bp = packAp + (((size_t)n * PADH + h0) * PADW + lane) * 2;
#pragma unroll
    for (int r = 0; r < 4; ++r)
#pragma unroll
        for (int c = 0; c < 3; ++c) {
            ulonglong2 q = *reinterpret_cast<const ulonglong2*>(
                bp + ((size_t)r * PADW + c) * 2);
            a[r][c][0] = q.x;
            a[r][c][1] = q.y;
        }

    // Wave-uniform channel base -> scalar loads for weights/corr/coefs.
    int obase = __builtin_amdgcn_readfirstlane(cg * 64 + (wv << 4));
    const u64* wbase = packW + (size_t)obase * 18;
    const int* cbase = corrW + obase * 8;

    bool top = (hp == 0), bot = (hp == NRP - 1);
    bool isL = (lane == 0), isR = (lane == NW - 1);
    int sl = n * NRP + hp;
    size_t pixoff = (size_t)n * NO * NHW_ + (size_t)h0 * NW + lane;

    for (int oo = 0; oo < 16; ++oo) {
        int o = obase + oo;
        const u64* wp = wbase + oo * 18;
        const int* cw = cbase + oo * 8;
        int pc0 = 0, pc1 = 0;
#pragma unroll
        for (int t = 0; t < 9; ++t) {
            const int kh = t / 3, kw = t - 3 * (t / 3);
            u64 w0 = wp[2 * t], w1 = wp[2 * t + 1];
            pc0 += __popcll(a[kh][kw][0] ^ w0) + __popcll(a[kh][kw][1] ^ w1);
            pc1 += __popcll(a[kh + 1][kw][0] ^ w0) + __popcll(a[kh + 1][kw][1] ^ w1);
        }
        int corrcol = isL ? cw[0] : (isR ? cw[1] : 0);
        int base = NK - corrcol;
        int d0 = base - 2 * pc0;
        int d1 = base - 2 * pc1;
        if (top) d0 -= cw[2] - (isL ? cw[4] : (isR ? cw[5] : 0));
        if (bot) d1 -= cw[3] - (isL ? cw[6] : (isR ? cw[7] : 0));

        if (MODE == 0 && act) {
            short* yp = yI + pixoff + (size_t)o * NHW_;
            yp[0]  = (short)d0;
            yp[NW] = (short)d1;
        }
        if (MODE <= 1) {
            int s = act ? (d0 + d1) : 0;
            int q = act ? (__mul24(d0, d0) + __mul24(d1, d1)) : 0;
#pragma unroll
            for (int off = 32; off; off >>= 1) {
                s += __shfl_down(s, off);
                q += __shfl_down(q, off);
            }
            if (lane == 0) {
                sumP[o * NSLOT + sl] = s;   // q <= 56*2*1152^2 = 1.49e8 < 2^31
                sqP[o * NSLOT + sl]  = q;
            }
        }
        if (MODE == 2 && act) {
            float ca = coefA[o], cb = coefB[o], al = alpha[o], b2 = bias2[o];
            size_t idx = pixoff + (size_t)o * NHW_;
            float t0 = fmaf(ca, (float)d0, cb) + x[idx];
            float t1 = fmaf(ca, (float)d1, cb) + x[idx + NW];
            t0 = t0 >= 0.f ? t0 : al * t0;
            t1 = t1 >= 0.f ? t1 : al * t1;
            out[idx]      = t0 + b2;
            out[idx + NW] = t1 + b2;
        }
    }
}

// ---------------------------------------------------------------------------
// K4: fold partial stats + scale + BN + bias1 into per-channel affine.
// 128 blocks x 64 threads; each block reduces 896 partials for one channel.
// ---------------------------------------------------------------------------
__global__ __launch_bounds__(64) void bn_coef2(const int* __restrict__ sumP,
                                               const int* __restrict__ sqP,
                                               const float* __restrict__ scaleW,
                                               const float* __restrict__ gamma,
                                               const float* __restrict__ beta,
                                               const float* __restrict__ bias1,
                                               float* __restrict__ coefA,
                                               float* __restrict__ coefB) {
    int o = blockIdx.x;
    int t = threadIdx.x;
    long long s = 0, q = 0;
    for (int i = t; i < NSLOT; i += 64) {
        s += sumP[o * NSLOT + i];
        q += sqP[o * NSLOT + i];
    }
#pragma unroll
    for (int off = 32; off; off >>= 1) {
        s += __shfl_down(s, off);
        q += __shfl_down(q, off);
    }
    if (t == 0) {
        double cnt = (double)NPIX;
        double mean = (double)s / cnt;
        double var = (double)q / cnt - mean * mean;
        if (var < 0.0) var = 0.0;
        float sc = scaleW[o];
        float rs = rsqrtf((float)((double)sc * (double)sc * var) + 1e-5f);
        float g = gamma[o];
        coefA[o] = sc * g * rs;
        coefB[o] = beta[o] - (float)((double)sc * mean) * g * rs + bias1[o];
    }
}

// ---------------------------------------------------------------------------
// K5: elementwise epilogue, 8 elems/thread vectorized.
// out = prelu(coefA*y + coefB + x) + bias2
// ---------------------------------------------------------------------------
__global__ __launch_bounds__(256) void final_store(const short* __restrict__ yI,
                                                   const float* __restrict__ x,
                                                   const float* __restrict__ coefA,
                                                   const float* __restrict__ coefB,
                                                   const float* __restrict__ alpha,
                                                   const float* __restrict__ bias2,
                                                   float* __restrict__ out) {
    const size_t ngroups = (size_t)NB * NO * NHW_ / 8;
    for (size_t g = (size_t)blockIdx.x * blockDim.x + threadIdx.x; g < ngroups;
         g += (size_t)gridDim.x * blockDim.x) {
        size_t i = g * 8;
        int o = (int)((i / NHW_) % NO);
        float a = coefA[o], bb = coefB[o], al = alpha[o], b2 = bias2[o];
        int4 yv = *reinterpret_cast<const int4*>(yI + i);
        float4 x0 = *reinterpret_cast<const float4*>(x + i);
        float4 x1 = *reinterpret_cast<const float4*>(x + i + 4);
        int q[4] = {yv.x, yv.y, yv.z, yv.w};
        float xs[8] = {x0.x, x0.y, x0.z, x0.w, x1.x, x1.y, x1.z, x1.w};
        float r[8];
#pragma unroll
        for (int j = 0; j < 4; ++j) {
            float lo = (float)(short)(q[j] & 0xffff);
            float hi = (float)(q[j] >> 16);
            float t0 = fmaf(a, lo, bb) + xs[2 * j];
            float t1 = fmaf(a, hi, bb) + xs[2 * j + 1];
            t0 = t0 >= 0.f ? t0 : al * t0;
            t1 = t1 >= 0.f ? t1 : al * t1;
            r[2 * j]     = t0 + b2;
            r[2 * j + 1] = t1 + b2;
        }
        float4 o0 = {r[0], r[1], r[2], r[3]};
        float4 o1 = {r[4], r[5], r[6], r[7]};
        *reinterpret_cast<float4*>(out + i)     = o0;
        *reinterpret_cast<float4*>(out + i + 4) = o1;
    }
}

// ---------------------------------------------------------------------------
// Workspace layout (bytes):
//   0        packAp  (padded bitplanes) 1,959,936
//   1959936  packW   (128*18 u64)          18,432
//   1978368  corrW   (128*8 i32)            4,096
//   1982464  scaleW  (128 f32)                512
//   1982976  coefA   (128 f32)                512
//   1983488  coefB   (128 f32)                512
//   1984000  sumP    (128*896 i32)        458,752
//   2442752  sqP     (128*896 i32)        458,752
//   2901504  yI      (int16)           25,690,112   -> total 28,591,616
// ---------------------------------------------------------------------------
extern "C" void kernel_launch(void* const* d_in, const int* in_sizes, int n_in,
                              void* d_out, int out_size, void* d_ws, size_t ws_size,
                              hipStream_t stream) {
    (void)in_sizes; (void)n_in; (void)out_size;
    const float* x     = (const float*)d_in[0];
    const float* bias0 = (const float*)d_in[1];
    const float* w     = (const float*)d_in[2];
    const float* gamma = (const float*)d_in[3];
    const float* beta  = (const float*)d_in[4];
    const float* bias1 = (const float*)d_in[5];
    const float* alpha = (const float*)d_in[6];
    const float* bias2 = (const float*)d_in[7];
    float* out = (float*)d_out;
    char* ws = (char*)d_ws;

    u64*   packAp = (u64*)ws;
    u64*   packW  = (u64*)(ws + 1959936);
    int*   corrW  = (int*)(ws + 1978368);
    float* scaleW = (float*)(ws + 1982464);
    float* coefA  = (float*)(ws + 1982976);
    float* coefB  = (float*)(ws + 1983488);
    int*   sumP   = (int*)(ws + 1984000);
    int*   sqP    = (int*)(ws + 2442752);
    short* yI     = (short*)(ws + 2901504);
    bool store = ws_size >= (size_t)2901504 + (size_t)NB * NO * NHW_ * 2;

    hipMemsetAsync(packAp, 0, PAD_BYTES, stream);
    pack_act<<<NPIX / 256, 256, 0, stream>>>(x, bias0, packAp);
    pack_wgt<<<NO, 64, 0, stream>>>(w, packW, scaleW, corrW);

    if (store) {
        conv_bin<0><<<NB * NRP * 2, 256, 0, stream>>>(
            packAp, packW, corrW, yI, sumP, sqP,
            nullptr, nullptr, nullptr, nullptr, nullptr, nullptr);
        bn_coef2<<<NO, 64, 0, stream>>>(sumP, sqP, scaleW, gamma, beta, bias1, coefA, coefB);
        final_store<<<2048, 256, 0, stream>>>(yI, x, coefA, coefB, alpha, bias2, out);
    } else {
        conv_bin<1><<<NB * NRP * 2, 256, 0, stream>>>(
            packAp, packW, corrW, nullptr, sumP, sqP,
            nullptr, nullptr, nullptr, nullptr, nullptr, nullptr);
        bn_coef2<<<NO, 64, 0, stream>>>(sumP, sqP, scaleW, gamma, beta, bias1, coefA, coefB);
        conv_bin<2><<<NB * NRP * 2, 256, 0, stream>>>(
            packAp, packW, corrW, nullptr, sumP, sqP,
            coefA, coefB, alpha, bias2, x, out);
    }
}